// Round 1
// baseline (3986.674 us; speedup 1.0000x reference)
//
#include <hip/hip_runtime.h>
#include <hip/hip_bf16.h>
#include <math.h>

#define H_DIM 2048
#define F_DIM 768
#define E_NUM 32
#define TOPK 4
#define SF_DIM 5632
#define T_NUM 2048

typedef __attribute__((ext_vector_type(8))) short short8v;
typedef __attribute__((ext_vector_type(4))) float f4;

__device__ __forceinline__ unsigned short f2b(float f) {
  unsigned int u = __float_as_uint(f);
  u += 0x7FFFu + ((u >> 16) & 1u);
  return (unsigned short)(u >> 16);
}

__device__ __forceinline__ f4 mfma16(short8v a, short8v b, f4 c) {
  return __builtin_amdgcn_mfma_f32_16x16x32_bf16(a, b, c, 0, 0, 0);
}

// ---------------------------------------------------------------------------
// Router: one block (64 threads) per token. fp32 logits, softmax, top-4,
// normalized weights, atomic scatter to per-expert lists. Also sigmoid(x@seg).
// ---------------------------------------------------------------------------
__global__ __launch_bounds__(64) void router_kernel(
    const float* __restrict__ x, const float* __restrict__ gate_w,
    const float* __restrict__ seg, int* __restrict__ cnt,
    int* __restrict__ toklist, float* __restrict__ wtlist,
    float* __restrict__ sigbuf) {
  const int t = blockIdx.x;
  const int l = threadIdx.x;
  const int e = l & 31;
  const int half = l >> 5;
  const float* xr = x + (size_t)t * H_DIM;

  float acc = 0.0f, aseg = 0.0f;
  const int h0 = half * (H_DIM / 2);
  for (int h = 0; h < H_DIM / 2; ++h) {
    float xv = xr[h0 + h];
    acc += xv * gate_w[(h0 + h) * E_NUM + e];
    aseg += xv * seg[h0 + h];
  }
  acc += __shfl_xor(acc, 32, 64);
  aseg += __shfl_xor(aseg, 32, 64);

  // softmax over 32 experts (values replicated in both 32-lane halves)
  float m = acc;
#pragma unroll
  for (int mask = 16; mask >= 1; mask >>= 1) m = fmaxf(m, __shfl_xor(m, mask, 64));
  float p = expf(acc - m);
  float s = p;
#pragma unroll
  for (int mask = 16; mask >= 1; mask >>= 1) s += __shfl_xor(s, mask, 64);
  p /= s;

  float pv = p;
  int ids[TOPK];
  float wv[TOPK];
  float wsum = 0.0f;
#pragma unroll
  for (int k = 0; k < TOPK; ++k) {
    float mv = pv;
    int mi = e;
#pragma unroll
    for (int mask = 16; mask >= 1; mask >>= 1) {
      float ov = __shfl_xor(mv, mask, 64);
      int oi = __shfl_xor(mi, mask, 64);
      if (ov > mv || (ov == mv && oi < mi)) { mv = ov; mi = oi; }
    }
    ids[k] = mi;
    wv[k] = mv;
    wsum += mv;
    if (e == mi) pv = -1.0f;
  }

  if (l < TOPK) {
    int id = ids[l];
    float w = wv[l] / wsum;
    int pos = atomicAdd(&cnt[id], 1);
    toklist[id * T_NUM + pos] = t;
    wtlist[id * T_NUM + pos] = w;
  }
  if (l == 0) sigbuf[t] = 1.0f / (1.0f + expf(-aseg));
}

// ---------------------------------------------------------------------------
// Shared GEMM1: Hs[T][SF] = silu(x@sg) * (x@su), bf16 output.
// Block tile 64x64, 4 waves (one 16-col n-tile each, 4 m-tiles).
// A (x) staged in LDS as bf16; B (sg/su) read direct from global fp32.
// ---------------------------------------------------------------------------
__global__ __launch_bounds__(256) void shared_gemm1(
    const float* __restrict__ x, const float* __restrict__ sg,
    const float* __restrict__ su, unsigned short* __restrict__ Hs) {
  __shared__ unsigned short Xl[64 * 40];
  const int m0 = blockIdx.x * 64;
  const int n0 = blockIdx.y * 64;
  const int tid = threadIdx.x;
  const int lane = tid & 63, w = tid >> 6;
  const int q = lane >> 4, ln = lane & 15;
  const int colw = n0 + w * 16 + ln;

  const f4 zero = {0.0f, 0.0f, 0.0f, 0.0f};
  f4 accg[4], accu[4];
#pragma unroll
  for (int i = 0; i < 4; ++i) { accg[i] = zero; accu[i] = zero; }

  const int srow = tid >> 2, sseg = tid & 3;
  const float* xsrc = x + (size_t)(m0 + srow) * H_DIM;

  for (int k0 = 0; k0 < H_DIM; k0 += 32) {
    float4 v0 = *(const float4*)(xsrc + k0 + sseg * 8);
    float4 v1 = *(const float4*)(xsrc + k0 + sseg * 8 + 4);
    unsigned short* dst = &Xl[srow * 40 + sseg * 8];
    dst[0] = f2b(v0.x); dst[1] = f2b(v0.y); dst[2] = f2b(v0.z); dst[3] = f2b(v0.w);
    dst[4] = f2b(v1.x); dst[5] = f2b(v1.y); dst[6] = f2b(v1.z); dst[7] = f2b(v1.w);
    __syncthreads();

    const float* bgp = sg + (size_t)(k0 + 8 * q) * SF_DIM + colw;
    const float* bup = su + (size_t)(k0 + 8 * q) * SF_DIM + colw;
    short8v bg, bu;
#pragma unroll
    for (int j = 0; j < 8; ++j) {
      bg[j] = (short)f2b(bgp[j * SF_DIM]);
      bu[j] = (short)f2b(bup[j * SF_DIM]);
    }
#pragma unroll
    for (int mt = 0; mt < 4; ++mt) {
      short8v a = *(const short8v*)&Xl[(mt * 16 + ln) * 40 + 8 * q];
      accg[mt] = mfma16(a, bg, accg[mt]);
      accu[mt] = mfma16(a, bu, accu[mt]);
    }
    __syncthreads();
  }

#pragma unroll
  for (int mt = 0; mt < 4; ++mt) {
#pragma unroll
    for (int r = 0; r < 4; ++r) {
      int row = m0 + mt * 16 + 4 * q + r;
      float g = accg[mt][r], u = accu[mt][r];
      float hv = g / (1.0f + __expf(-g)) * u;
      Hs[(size_t)row * SF_DIM + colw] = f2b(hv);
    }
  }
}

// ---------------------------------------------------------------------------
// Shared GEMM2: out[T][H] = sig[t] * (Hs @ sd). Plain stores (owns d_out).
// ---------------------------------------------------------------------------
__global__ __launch_bounds__(256) void shared_gemm2(
    const unsigned short* __restrict__ Hs, const float* __restrict__ sd,
    const float* __restrict__ sigbuf, float* __restrict__ out) {
  __shared__ unsigned short Al[64 * 40];
  const int m0 = blockIdx.x * 64;
  const int n0 = blockIdx.y * 64;
  const int tid = threadIdx.x;
  const int lane = tid & 63, w = tid >> 6;
  const int q = lane >> 4, ln = lane & 15;
  const int colw = n0 + w * 16 + ln;

  const f4 zero = {0.0f, 0.0f, 0.0f, 0.0f};
  f4 acc[4];
#pragma unroll
  for (int i = 0; i < 4; ++i) acc[i] = zero;

  const int srow = tid >> 2, sseg = tid & 3;
  const unsigned short* hsrc = Hs + (size_t)(m0 + srow) * SF_DIM;

  for (int k0 = 0; k0 < SF_DIM; k0 += 32) {
    *(short8v*)&Al[srow * 40 + sseg * 8] = *(const short8v*)(hsrc + k0 + sseg * 8);
    __syncthreads();

    const float* bp = sd + (size_t)(k0 + 8 * q) * H_DIM + colw;
    short8v b;
#pragma unroll
    for (int j = 0; j < 8; ++j) b[j] = (short)f2b(bp[j * H_DIM]);
#pragma unroll
    for (int mt = 0; mt < 4; ++mt) {
      short8v a = *(const short8v*)&Al[(mt * 16 + ln) * 40 + 8 * q];
      acc[mt] = mfma16(a, b, acc[mt]);
    }
    __syncthreads();
  }

#pragma unroll
  for (int mt = 0; mt < 4; ++mt) {
#pragma unroll
    for (int r = 0; r < 4; ++r) {
      int row = m0 + mt * 16 + 4 * q + r;
      out[(size_t)row * H_DIM + colw] = sigbuf[row] * acc[mt][r];
    }
  }
}

// ---------------------------------------------------------------------------
// Expert FFN (fused): per block, 32 tokens of one expert.
// GEMM1: h = silu(X@wg_e)*(X@wu_e) -> bf16 in LDS (32x768, padded to 776).
// GEMM2: out += cw * (h @ wd_e) via atomicAdd.
// Grid: (64 token-tiles, 32 experts); early-exit tiles beyond count.
// ---------------------------------------------------------------------------
__global__ __launch_bounds__(256) void expert_ffn(
    const float* __restrict__ x, const float* __restrict__ wg,
    const float* __restrict__ wu, const float* __restrict__ wd,
    const int* __restrict__ cnt, const int* __restrict__ toklist,
    const float* __restrict__ wtlist, float* __restrict__ out) {
  const int e = blockIdx.y;
  const int tile = blockIdx.x;
  const int count = cnt[e];
  if (tile * 32 >= count) return;

  __shared__ int ids[32];
  __shared__ float cws[32];
  __shared__ unsigned short Xl[32 * 40];
  __shared__ unsigned short Hl[32 * 776];

  const int tid = threadIdx.x;
  const int lane = tid & 63, w = tid >> 6;
  const int q = lane >> 4, ln = lane & 15;

  if (tid < 32) {
    int idx = tile * 32 + tid;
    if (idx < count) {
      ids[tid] = toklist[e * T_NUM + idx];
      cws[tid] = wtlist[e * T_NUM + idx];
    } else {
      ids[tid] = 0;
      cws[tid] = 0.0f;
    }
  }
  __syncthreads();

  const float* wge = wg + (size_t)e * H_DIM * F_DIM;
  const float* wue = wu + (size_t)e * H_DIM * F_DIM;
  const float* wde = wd + (size_t)e * F_DIM * H_DIM;

  const int srow = tid >> 3, sseg = tid & 7;
  const float* xrow = x + (size_t)ids[srow] * H_DIM;
  const f4 zero = {0.0f, 0.0f, 0.0f, 0.0f};

  // ---- GEMM1: 3 sub-chunks of 64 cols per wave (wave covers 192 cols) ----
  for (int sub = 0; sub < 3; ++sub) {
    const int nbase = w * 192 + sub * 64;
    f4 ag[2][4], au[2][4];
#pragma unroll
    for (int mt = 0; mt < 2; ++mt)
#pragma unroll
      for (int nt = 0; nt < 4; ++nt) { ag[mt][nt] = zero; au[mt][nt] = zero; }

    for (int k0 = 0; k0 < H_DIM; k0 += 32) {
      float4 v = *(const float4*)(xrow + k0 + sseg * 4);
      unsigned short* dst = &Xl[srow * 40 + sseg * 4];
      dst[0] = f2b(v.x); dst[1] = f2b(v.y); dst[2] = f2b(v.z); dst[3] = f2b(v.w);
      __syncthreads();

      short8v a0 = *(const short8v*)&Xl[ln * 40 + 8 * q];
      short8v a1 = *(const short8v*)&Xl[(16 + ln) * 40 + 8 * q];
#pragma unroll
      for (int nt = 0; nt < 4; ++nt) {
        const int col = nbase + nt * 16 + ln;
        const float* bgp = wge + (size_t)(k0 + 8 * q) * F_DIM + col;
        const float* bup = wue + (size_t)(k0 + 8 * q) * F_DIM + col;
        short8v bg, bu;
#pragma unroll
        for (int j = 0; j < 8; ++j) {
          bg[j] = (short)f2b(bgp[j * F_DIM]);
          bu[j] = (short)f2b(bup[j * F_DIM]);
        }
        ag[0][nt] = mfma16(a0, bg, ag[0][nt]);
        ag[1][nt] = mfma16(a1, bg, ag[1][nt]);
        au[0][nt] = mfma16(a0, bu, au[0][nt]);
        au[1][nt] = mfma16(a1, bu, au[1][nt]);
      }
      __syncthreads();
    }

#pragma unroll
    for (int mt = 0; mt < 2; ++mt)
#pragma unroll
      for (int nt = 0; nt < 4; ++nt)
#pragma unroll
        for (int r = 0; r < 4; ++r) {
          int row = mt * 16 + 4 * q + r;
          int col = nbase + nt * 16 + ln;
          float g = ag[mt][nt][r], u = au[mt][nt][r];
          Hl[row * 776 + col] = f2b(g / (1.0f + __expf(-g)) * u);
        }
  }
  __syncthreads();

  // ---- GEMM2: 8 sub-chunks of 64 cols per wave (wave covers 512 cols) ----
  for (int sub = 0; sub < 8; ++sub) {
    const int nbase = w * 512 + sub * 64;
    f4 acc[2][4];
#pragma unroll
    for (int mt = 0; mt < 2; ++mt)
#pragma unroll
      for (int nt = 0; nt < 4; ++nt) acc[mt][nt] = zero;

    for (int k0 = 0; k0 < F_DIM; k0 += 32) {
      short8v a0 = *(const short8v*)&Hl[ln * 776 + k0 + 8 * q];
      short8v a1 = *(const short8v*)&Hl[(16 + ln) * 776 + k0 + 8 * q];
#pragma unroll
      for (int nt = 0; nt < 4; ++nt) {
        const int col = nbase + nt * 16 + ln;
        const float* bp = wde + (size_t)(k0 + 8 * q) * H_DIM + col;
        short8v b;
#pragma unroll
        for (int j = 0; j < 8; ++j) b[j] = (short)f2b(bp[j * H_DIM]);
        acc[0][nt] = mfma16(a0, b, acc[0][nt]);
        acc[1][nt] = mfma16(a1, b, acc[1][nt]);
      }
    }

#pragma unroll
    for (int mt = 0; mt < 2; ++mt)
#pragma unroll
      for (int nt = 0; nt < 4; ++nt)
#pragma unroll
        for (int r = 0; r < 4; ++r) {
          int row = mt * 16 + 4 * q + r;
          int col = nbase + nt * 16 + ln;
          atomicAdd(&out[(size_t)ids[row] * H_DIM + col], cws[row] * acc[mt][nt][r]);
        }
  }
}

// ---------------------------------------------------------------------------
extern "C" void kernel_launch(void* const* d_in, const int* in_sizes, int n_in,
                              void* d_out, int out_size, void* d_ws, size_t ws_size,
                              hipStream_t stream) {
  const float* x      = (const float*)d_in[0];
  const float* gate_w = (const float*)d_in[1];
  const float* wg     = (const float*)d_in[2];
  const float* wu     = (const float*)d_in[3];
  const float* wd     = (const float*)d_in[4];
  const float* sg     = (const float*)d_in[5];
  const float* su     = (const float*)d_in[6];
  const float* sd     = (const float*)d_in[7];
  const float* seg    = (const float*)d_in[8];
  float* out = (float*)d_out;

  char* ws = (char*)d_ws;
  int* cnt = (int*)ws;                                  // 256 B (32 ints used)
  int* toklist = (int*)(ws + 256);                      // 32*2048*4 = 256 KB
  float* wtlist = (float*)(ws + 256 + 262144);          // 256 KB
  float* sigbuf = (float*)(ws + 256 + 524288);          // 8 KB
  unsigned short* Hs = (unsigned short*)(ws + 256 + 524288 + 8192);  // 22.5 MB bf16

  hipMemsetAsync(cnt, 0, 256, stream);
  router_kernel<<<T_NUM, 64, 0, stream>>>(x, gate_w, seg, cnt, toklist, wtlist, sigbuf);
  shared_gemm1<<<dim3(32, 88), 256, 0, stream>>>(x, sg, su, Hs);
  shared_gemm2<<<dim3(32, 32), 256, 0, stream>>>(Hs, sd, sigbuf, out);
  expert_ffn<<<dim3(64, 32), 256, 0, stream>>>(x, wg, wu, wd, cnt, toklist, wtlist, out);
}

// Round 2
// 1310.860 us; speedup vs baseline: 3.0413x; 3.0413x over previous
//
#include <hip/hip_runtime.h>
#include <hip/hip_bf16.h>
#include <math.h>

#define H_DIM 2048
#define F_DIM 768
#define E_NUM 32
#define TOPK 4
#define SF_DIM 5632
#define T_NUM 2048
#define P_MAX (T_NUM * TOPK)

typedef __attribute__((ext_vector_type(8))) short short8v;
typedef __attribute__((ext_vector_type(4))) float f4;
typedef unsigned short u16;

__device__ __forceinline__ u16 f2b(float f) {
  unsigned int u = __float_as_uint(f);
  u += 0x7FFFu + ((u >> 16) & 1u);
  return (u16)(u >> 16);
}

__device__ __forceinline__ f4 mfma16(short8v a, short8v b, f4 c) {
  return __builtin_amdgcn_mfma_f32_16x16x32_bf16(a, b, c, 0, 0, 0);
}

// async 16B global->LDS (wave-uniform base + lane*16 ordering)
__device__ __forceinline__ void gld16(const u16* g, u16* l) {
  __builtin_amdgcn_global_load_lds(
      (const __attribute__((address_space(1))) void*)g,
      (__attribute__((address_space(3))) void*)l, 16, 0, 0);
}

// ---------------------------------------------------------------------------
// Router: 1 block (64 threads) per token. fp32 logits/softmax/top-4.
// Outputs per-expert token lists + per-token slot map (for combine).
// ---------------------------------------------------------------------------
__global__ __launch_bounds__(64) void router_kernel(
    const float* __restrict__ x, const float* __restrict__ gate_w,
    const float* __restrict__ seg, int* __restrict__ cnt,
    int* __restrict__ toklist, int* __restrict__ slotE,
    int* __restrict__ slotPos, float* __restrict__ wt4,
    float* __restrict__ sigbuf) {
  const int t = blockIdx.x;
  const int l = threadIdx.x;
  const int e = l & 31;
  const int half = l >> 5;
  const float* xr = x + (size_t)t * H_DIM;

  float acc = 0.0f, aseg = 0.0f;
  const int h0 = half * (H_DIM / 2);
  for (int h = 0; h < H_DIM / 2; ++h) {
    float xv = xr[h0 + h];
    acc += xv * gate_w[(h0 + h) * E_NUM + e];
    aseg += xv * seg[h0 + h];
  }
  acc += __shfl_xor(acc, 32, 64);
  aseg += __shfl_xor(aseg, 32, 64);

  float m = acc;
#pragma unroll
  for (int mask = 16; mask >= 1; mask >>= 1) m = fmaxf(m, __shfl_xor(m, mask, 64));
  float p = expf(acc - m);
  float s = p;
#pragma unroll
  for (int mask = 16; mask >= 1; mask >>= 1) s += __shfl_xor(s, mask, 64);
  p /= s;

  float pv = p;
  int ids[TOPK];
  float wv[TOPK];
  float wsum = 0.0f;
#pragma unroll
  for (int k = 0; k < TOPK; ++k) {
    float mv = pv;
    int mi = e;
#pragma unroll
    for (int mask = 16; mask >= 1; mask >>= 1) {
      float ov = __shfl_xor(mv, mask, 64);
      int oi = __shfl_xor(mi, mask, 64);
      if (ov > mv || (ov == mv && oi < mi)) { mv = ov; mi = oi; }
    }
    ids[k] = mi;
    wv[k] = mv;
    wsum += mv;
    if (e == mi) pv = -1.0f;
  }

  if (l < TOPK) {
    int id = ids[l];
    float w = wv[l] / wsum;
    int pos = atomicAdd(&cnt[id], 1);
    toklist[id * T_NUM + pos] = t;
    slotE[t * TOPK + l] = id;
    slotPos[t * TOPK + l] = pos;
    wt4[t * TOPK + l] = w;
  }
  if (l == 0) sigbuf[t] = 1.0f / (1.0f + expf(-aseg));
}

// exclusive prefix over 32 counts
__global__ void offs_kernel(const int* __restrict__ cnt, int* __restrict__ offs) {
  if (threadIdx.x == 0) {
    int s = 0;
    for (int e = 0; e < E_NUM; ++e) { offs[e] = s; s += cnt[e]; }
  }
}

// x fp32 -> bf16 (row-major, no transpose). 8 elems/thread.
__global__ __launch_bounds__(256) void cvt_x(const float* __restrict__ in,
                                             u16* __restrict__ out) {
  int i = blockIdx.x * 256 + threadIdx.x;
  const float4* p = (const float4*)in + (size_t)i * 2;
  float4 a = p[0], b = p[1];
  short8v o;
  o[0] = (short)f2b(a.x); o[1] = (short)f2b(a.y);
  o[2] = (short)f2b(a.z); o[3] = (short)f2b(a.w);
  o[4] = (short)f2b(b.x); o[5] = (short)f2b(b.y);
  o[6] = (short)f2b(b.z); o[7] = (short)f2b(b.w);
  *(short8v*)(out + (size_t)i * 8) = o;
}

// fp32 [R][C] -> bf16 [C][R] (per-z matrix), 64x64 tiles via LDS
__global__ __launch_bounds__(256) void transpose_cvt(
    const float* __restrict__ in, u16* __restrict__ out, int R, int C) {
  in += (size_t)blockIdx.z * R * C;
  out += (size_t)blockIdx.z * R * C;
  const int r0 = blockIdx.y * 64;
  const int c0 = blockIdx.x * 64;
  __shared__ u16 tile[64][72];
  const int tid = threadIdx.x;
  const int tr = tid >> 2, tseg = tid & 3;
  const float* ip = in + (size_t)(r0 + tr) * C + c0 + tseg * 16;
#pragma unroll
  for (int j = 0; j < 4; ++j) {
    float4 v = *(const float4*)(ip + j * 4);
    u16* d = &tile[tr][tseg * 16 + j * 4];
    d[0] = f2b(v.x); d[1] = f2b(v.y); d[2] = f2b(v.z); d[3] = f2b(v.w);
  }
  __syncthreads();
  u16 tmp[16];
#pragma unroll
  for (int j = 0; j < 16; ++j) tmp[j] = tile[tseg * 16 + j][tr];
  u16* op = out + (size_t)(c0 + tr) * R + r0 + tseg * 16;
  *(short8v*)op = *(short8v*)&tmp[0];
  *(short8v*)(op + 8) = *(short8v*)&tmp[8];
}

// ---------------------------------------------------------------------------
// Fused gate+up GEMM: H = silu(A@Bg^T)*(A@Bu^T), bf16 out.
// BM=128, BN=64, BK=32. A rows gathered via ids[] (direct or toklist).
// Bg/Bu are B^T [N][K] bf16. LDS chunk-swizzle c=(s+(r>>1))&3 -> 2-way free.
// ---------------------------------------------------------------------------
__global__ __launch_bounds__(256) void gemm_gu(
    const u16* __restrict__ A, const u16* __restrict__ Bg,
    const u16* __restrict__ Bu, u16* __restrict__ Hout,
    int K, int N, int gather, const int* __restrict__ cnt,
    const int* __restrict__ toklist, const int* __restrict__ offs) {
  const int e = blockIdx.z;
  const int mtile = blockIdx.y;
  const int n0 = blockIdx.x * 64;
  int count = 1 << 30, obase = 0;
  if (gather) {
    count = cnt[e];
    if (mtile * 128 >= count) return;
    obase = offs[e];
    Bg += (size_t)e * N * K;
    Bu += (size_t)e * N * K;
  }

  __shared__ u16 As[128 * 32];
  __shared__ u16 Bgs[64 * 32];
  __shared__ u16 Bus[64 * 32];
  __shared__ int ids[128];

  const int tid = threadIdx.x;
  if (tid < 128) {
    int idx = mtile * 128 + tid;
    ids[tid] = gather ? toklist[e * T_NUM + min(idx, count - 1)] : idx;
  }
  __syncthreads();

  const int s = tid & 3, r0 = tid >> 2;
  const int cA0 = (s + (r0 >> 1)) & 3;
  const int cA1 = (s + ((r0 + 64) >> 1)) & 3;
  const u16* ap0 = A + (size_t)ids[r0] * K + cA0 * 8;
  const u16* ap1 = A + (size_t)ids[r0 + 64] * K + cA1 * 8;
  u16* al0 = As + tid * 8;
  u16* al1 = As + tid * 8 + 2048;
  const u16* bgp = Bg + (size_t)(n0 + r0) * K + cA0 * 8;
  const u16* bup = Bu + (size_t)(n0 + r0) * K + cA0 * 8;
  u16* bgl = Bgs + tid * 8;
  u16* bul = Bus + tid * 8;

  const int lane = tid & 63, w = tid >> 6;
  const int w0 = w & 1, w1 = w >> 1;
  const int ln = lane & 15, q = lane >> 4;

  int aoff[4], boff[2];
#pragma unroll
  for (int mt = 0; mt < 4; ++mt) {
    int r = w0 * 64 + mt * 16 + ln;
    aoff[mt] = r * 32 + ((q - (r >> 1)) & 3) * 8;
  }
#pragma unroll
  for (int nt = 0; nt < 2; ++nt) {
    int r = w1 * 32 + nt * 16 + ln;
    boff[nt] = r * 32 + ((q - (r >> 1)) & 3) * 8;
  }

  const f4 zero = {0.f, 0.f, 0.f, 0.f};
  f4 accg[4][2], accu[4][2];
#pragma unroll
  for (int mt = 0; mt < 4; ++mt)
#pragma unroll
    for (int nt = 0; nt < 2; ++nt) { accg[mt][nt] = zero; accu[mt][nt] = zero; }

  for (int k0 = 0; k0 < K; k0 += 32) {
    gld16(ap0 + k0, al0);
    gld16(ap1 + k0, al1);
    gld16(bgp + k0, bgl);
    gld16(bup + k0, bul);
    __syncthreads();
    short8v av[4], bgv[2], buv[2];
#pragma unroll
    for (int mt = 0; mt < 4; ++mt) av[mt] = *(const short8v*)&As[aoff[mt]];
#pragma unroll
    for (int nt = 0; nt < 2; ++nt) {
      bgv[nt] = *(const short8v*)&Bgs[boff[nt]];
      buv[nt] = *(const short8v*)&Bus[boff[nt]];
    }
#pragma unroll
    for (int mt = 0; mt < 4; ++mt)
#pragma unroll
      for (int nt = 0; nt < 2; ++nt) {
        accg[mt][nt] = mfma16(av[mt], bgv[nt], accg[mt][nt]);
        accu[mt][nt] = mfma16(av[mt], buv[nt], accu[mt][nt]);
      }
    __syncthreads();
  }

#pragma unroll
  for (int mt = 0; mt < 4; ++mt)
#pragma unroll
    for (int nt = 0; nt < 2; ++nt)
#pragma unroll
      for (int r = 0; r < 4; ++r) {
        int m = w0 * 64 + mt * 16 + 4 * q + r;
        int idx = mtile * 128 + m;
        if (idx < count) {
          int n = n0 + w1 * 32 + nt * 16 + ln;
          float g = accg[mt][nt][r], u = accu[mt][nt][r];
          float h = g / (1.0f + __expf(-g)) * u;
          Hout[(size_t)(obase + idx) * N + n] = f2b(h);
        }
      }
}

// ---------------------------------------------------------------------------
// Plain GEMM: D = A@Bt^T (fp32 out). BM=128, BN=128, BK=32.
// gather mode: A rows are a contiguous expert segment [offs[e], offs[e]+cnt).
// ---------------------------------------------------------------------------
__global__ __launch_bounds__(256) void gemm_dn(
    const u16* __restrict__ A, const u16* __restrict__ Bt,
    float* __restrict__ D, int K, int N, int gather,
    const int* __restrict__ cnt, const int* __restrict__ offs) {
  const int e = blockIdx.z;
  const int mtile = blockIdx.y;
  const int n0 = blockIdx.x * 128;
  int count = 1 << 30, obase = 0;
  if (gather) {
    count = cnt[e];
    if (mtile * 128 >= count) return;
    obase = offs[e];
    Bt += (size_t)e * N * K;
  }

  __shared__ u16 As[128 * 32];
  __shared__ u16 Bs[128 * 32];
  __shared__ int ids[128];

  const int tid = threadIdx.x;
  if (tid < 128) {
    int idx = mtile * 128 + tid;
    ids[tid] = gather ? (obase + min(idx, count - 1)) : idx;
  }
  __syncthreads();

  const int s = tid & 3, r0 = tid >> 2;
  const int cA0 = (s + (r0 >> 1)) & 3;
  const int cA1 = (s + ((r0 + 64) >> 1)) & 3;
  const u16* ap0 = A + (size_t)ids[r0] * K + cA0 * 8;
  const u16* ap1 = A + (size_t)ids[r0 + 64] * K + cA1 * 8;
  u16* al0 = As + tid * 8;
  u16* al1 = As + tid * 8 + 2048;
  const u16* bp0 = Bt + (size_t)(n0 + r0) * K + cA0 * 8;
  const u16* bp1 = Bt + (size_t)(n0 + r0 + 64) * K + cA1 * 8;
  u16* bl0 = Bs + tid * 8;
  u16* bl1 = Bs + tid * 8 + 2048;

  const int lane = tid & 63, w = tid >> 6;
  const int w0 = w & 1, w1 = w >> 1;
  const int ln = lane & 15, q = lane >> 4;

  int aoff[4], boff[4];
#pragma unroll
  for (int mt = 0; mt < 4; ++mt) {
    int r = w0 * 64 + mt * 16 + ln;
    aoff[mt] = r * 32 + ((q - (r >> 1)) & 3) * 8;
    int rb = w1 * 64 + mt * 16 + ln;
    boff[mt] = rb * 32 + ((q - (rb >> 1)) & 3) * 8;
  }

  const f4 zero = {0.f, 0.f, 0.f, 0.f};
  f4 acc[4][4];
#pragma unroll
  for (int mt = 0; mt < 4; ++mt)
#pragma unroll
    for (int nt = 0; nt < 4; ++nt) acc[mt][nt] = zero;

  for (int k0 = 0; k0 < K; k0 += 32) {
    gld16(ap0 + k0, al0);
    gld16(ap1 + k0, al1);
    gld16(bp0 + k0, bl0);
    gld16(bp1 + k0, bl1);
    __syncthreads();
    short8v av[4], bv[4];
#pragma unroll
    for (int i = 0; i < 4; ++i) {
      av[i] = *(const short8v*)&As[aoff[i]];
      bv[i] = *(const short8v*)&Bs[boff[i]];
    }
#pragma unroll
    for (int mt = 0; mt < 4; ++mt)
#pragma unroll
      for (int nt = 0; nt < 4; ++nt)
        acc[mt][nt] = mfma16(av[mt], bv[nt], acc[mt][nt]);
    __syncthreads();
  }

#pragma unroll
  for (int mt = 0; mt < 4; ++mt)
#pragma unroll
    for (int nt = 0; nt < 4; ++nt)
#pragma unroll
      for (int r = 0; r < 4; ++r) {
        int m = w0 * 64 + mt * 16 + 4 * q + r;
        int idx = mtile * 128 + m;
        if (idx < count) {
          int n = n0 + w1 * 64 + nt * 16 + ln;
          D[(size_t)(obase + idx) * N + n] = acc[mt][nt][r];
        }
      }
}

// ---------------------------------------------------------------------------
// Final combine: out[t] = sig[t]*sharedD[t] + sum_k wt[t][k]*Dh[slot(t,k)]
// ---------------------------------------------------------------------------
__global__ __launch_bounds__(256) void combine_kernel(
    const float* __restrict__ sD, const float* __restrict__ Dh,
    const float* __restrict__ sig, const float* __restrict__ wt4,
    const int* __restrict__ slotE, const int* __restrict__ slotPos,
    const int* __restrict__ offs, float* __restrict__ out) {
  const int t = blockIdx.x;
  const int c = threadIdx.x * 8;
  const float sg = sig[t];
  const float* sp = sD + (size_t)t * H_DIM + c;
  float4 a0 = *(const float4*)sp;
  float4 a1 = *(const float4*)(sp + 4);
  float o[8];
  o[0] = sg * a0.x; o[1] = sg * a0.y; o[2] = sg * a0.z; o[3] = sg * a0.w;
  o[4] = sg * a1.x; o[5] = sg * a1.y; o[6] = sg * a1.z; o[7] = sg * a1.w;
#pragma unroll
  for (int k = 0; k < TOPK; ++k) {
    int ee = slotE[t * TOPK + k];
    int pp = offs[ee] + slotPos[t * TOPK + k];
    float w = wt4[t * TOPK + k];
    const float* dp = Dh + (size_t)pp * H_DIM + c;
    float4 d0 = *(const float4*)dp;
    float4 d1 = *(const float4*)(dp + 4);
    o[0] += w * d0.x; o[1] += w * d0.y; o[2] += w * d0.z; o[3] += w * d0.w;
    o[4] += w * d1.x; o[5] += w * d1.y; o[6] += w * d1.z; o[7] += w * d1.w;
  }
  float* op = out + (size_t)t * H_DIM + c;
  float4 r0 = {o[0], o[1], o[2], o[3]};
  float4 r1 = {o[4], o[5], o[6], o[7]};
  *(float4*)op = r0;
  *(float4*)(op + 4) = r1;
}

// ---------------------------------------------------------------------------
extern "C" void kernel_launch(void* const* d_in, const int* in_sizes, int n_in,
                              void* d_out, int out_size, void* d_ws, size_t ws_size,
                              hipStream_t stream) {
  const float* x      = (const float*)d_in[0];
  const float* gate_w = (const float*)d_in[1];
  const float* wg     = (const float*)d_in[2];
  const float* wu     = (const float*)d_in[3];
  const float* wd     = (const float*)d_in[4];
  const float* sg     = (const float*)d_in[5];
  const float* su     = (const float*)d_in[6];
  const float* sd     = (const float*)d_in[7];
  const float* seg    = (const float*)d_in[8];
  float* out = (float*)d_out;

  char* p = (char*)d_ws;
  auto alloc = [&](size_t bytes) {
    char* r = p;
    p += (bytes + 255) & ~(size_t)255;
    return r;
  };
  int* cnt      = (int*)alloc(E_NUM * 4);
  int* offs     = (int*)alloc(E_NUM * 4);
  int* toklist  = (int*)alloc((size_t)E_NUM * T_NUM * 4);
  int* slotE    = (int*)alloc((size_t)T_NUM * TOPK * 4);
  int* slotPos  = (int*)alloc((size_t)T_NUM * TOPK * 4);
  float* wt4    = (float*)alloc((size_t)T_NUM * TOPK * 4);
  float* sigbuf = (float*)alloc((size_t)T_NUM * 4);
  u16* xb  = (u16*)alloc((size_t)T_NUM * H_DIM * 2);
  u16* sgT = (u16*)alloc((size_t)H_DIM * SF_DIM * 2);
  u16* suT = (u16*)alloc((size_t)H_DIM * SF_DIM * 2);
  u16* sdT = (u16*)alloc((size_t)H_DIM * SF_DIM * 2);
  u16* wgT = (u16*)alloc((size_t)E_NUM * H_DIM * F_DIM * 2);
  u16* wuT = (u16*)alloc((size_t)E_NUM * H_DIM * F_DIM * 2);
  u16* wdT = (u16*)alloc((size_t)E_NUM * H_DIM * F_DIM * 2);
  u16* Hs  = (u16*)alloc((size_t)T_NUM * SF_DIM * 2);
  u16* He  = (u16*)alloc((size_t)(P_MAX + 128) * F_DIM * 2);
  float* sharedD = (float*)alloc((size_t)T_NUM * H_DIM * 4);
  float* Dh      = (float*)alloc((size_t)P_MAX * H_DIM * 4);

  hipMemsetAsync(cnt, 0, E_NUM * 4, stream);
  router_kernel<<<T_NUM, 64, 0, stream>>>(x, gate_w, seg, cnt, toklist,
                                          slotE, slotPos, wt4, sigbuf);
  offs_kernel<<<1, 64, 0, stream>>>(cnt, offs);

  cvt_x<<<(T_NUM * H_DIM / 8) / 256, 256, 0, stream>>>(x, xb);
  transpose_cvt<<<dim3(SF_DIM / 64, H_DIM / 64, 1), 256, 0, stream>>>(sg, sgT, H_DIM, SF_DIM);
  transpose_cvt<<<dim3(SF_DIM / 64, H_DIM / 64, 1), 256, 0, stream>>>(su, suT, H_DIM, SF_DIM);
  transpose_cvt<<<dim3(H_DIM / 64, SF_DIM / 64, 1), 256, 0, stream>>>(sd, sdT, SF_DIM, H_DIM);
  transpose_cvt<<<dim3(F_DIM / 64, H_DIM / 64, E_NUM), 256, 0, stream>>>(wg, wgT, H_DIM, F_DIM);
  transpose_cvt<<<dim3(F_DIM / 64, H_DIM / 64, E_NUM), 256, 0, stream>>>(wu, wuT, H_DIM, F_DIM);
  transpose_cvt<<<dim3(H_DIM / 64, F_DIM / 64, E_NUM), 256, 0, stream>>>(wd, wdT, F_DIM, H_DIM);

  // shared: Hs = silu(xb@sgT)*(xb@suT)   [2048 x 5632]
  gemm_gu<<<dim3(SF_DIM / 64, T_NUM / 128, 1), 256, 0, stream>>>(
      xb, sgT, suT, Hs, H_DIM, SF_DIM, 0, cnt, toklist, offs);
  // experts: He = silu(X_g@wgT)*(X_g@wuT)  [8192 x 768]
  gemm_gu<<<dim3(F_DIM / 64, T_NUM / 128, E_NUM), 256, 0, stream>>>(
      xb, wgT, wuT, He, H_DIM, F_DIM, 1, cnt, toklist, offs);
  // shared down: sharedD = Hs @ sdT   [2048 x 2048]
  gemm_dn<<<dim3(H_DIM / 128, T_NUM / 128, 1), 256, 0, stream>>>(
      Hs, sdT, sharedD, SF_DIM, H_DIM, 0, cnt, offs);
  // expert down: Dh = He @ wdT        [8192 x 2048]
  gemm_dn<<<dim3(H_DIM / 128, T_NUM / 128, E_NUM), 256, 0, stream>>>(
      He, wdT, Dh, F_DIM, H_DIM, 1, cnt, offs);

  combine_kernel<<<T_NUM, 256, 0, stream>>>(sharedD, Dh, sigbuf, wt4,
                                            slotE, slotPos, offs, out);
}